// Round 10
// baseline (664.453 us; speedup 1.0000x reference)
//
#include <hip/hip_runtime.h>

#define NODES 100000
#define EDGES 1600000

typedef __attribute__((ext_vector_type(4))) float floatx4;
typedef _Float16 h16;
typedef __attribute__((ext_vector_type(4))) _Float16 h16x4;
typedef __attribute__((ext_vector_type(8))) _Float16 h16x8;
typedef __attribute__((ext_vector_type(8))) _Float16 half8;

#define WSCALE 64.0f
#define WINV   (1.0f / 64.0f)

__device__ inline void load_lds16(void* lds, const void* g) {
    __builtin_amdgcn_global_load_lds((const __attribute__((address_space(1))) void*)g,
                                     (__attribute__((address_space(3))) void*)lds, 16, 0, 0);
}

__device__ inline float meta_w(unsigned m) {
    return (float)__builtin_bit_cast(h16, (unsigned short)(m & 0x7FFFu));
}

// ---------------- init packed accumulator ----------------
__global__ __launch_bounds__(256) void k_init(unsigned long long* __restrict__ packed, int n) {
    int i = blockIdx.x * 256 + threadIdx.x;
    if (i < n) packed[i] = 0ull;
}

// ---------------- fused: histogram+rank | W1 split | W2 split | x->fp16 ----------------
// blocks [0,6250): hist | [6250,6378): W1 | [6378,6634): W2 | [6634,19134): x16
__device__ inline void w_split(const float* W, h16* Wh, h16* Wl, int idx, int K) {
    int k = idx >> 8, nn = idx & 255;
    float v = W[idx] * WSCALE;
    h16 h = (h16)v;
    h16 l = (h16)(v - (float)h);
    Wh[nn * K + k] = h;
    Wl[nn * K + k] = l;
}

__global__ __launch_bounds__(256) void k_hist(unsigned long long* __restrict__ packed,
                                              unsigned short* __restrict__ rank,
                                              const int* __restrict__ col,
                                              const float* __restrict__ ew, int e,
                                              const float* __restrict__ W1, h16* __restrict__ W1h, h16* __restrict__ W1l,
                                              const float* __restrict__ W2, h16* __restrict__ W2h, h16* __restrict__ W2l,
                                              const float* __restrict__ x, h16* __restrict__ x16, int n) {
    int b = blockIdx.x;
    if (b < 6250) {
        int i = b * 256 + threadIdx.x;
        if (i < e) {
            int c = col[i];
            unsigned long long v = (1ull << 40) |
                (unsigned long long)__float2uint_rn(ew[i] * 1048576.0f);
            unsigned long long old = atomicAdd(&packed[c], v);
            rank[i] = (unsigned short)(old >> 40);
        }
    } else if (b < 6378) {
        w_split(W1, W1h, W1l, (b - 6250) * 256 + threadIdx.x, 128);
    } else if (b < 6634) {
        w_split(W2, W2h, W2l, (b - 6378) * 256 + threadIdx.x, 256);
    } else {
        int i = (b - 6634) * 256 + threadIdx.x;
        if (i < n * 32) {
            float4 v = reinterpret_cast<const float4*>(x)[i];
            h16x4 h;
            h.x = (h16)v.x; h.y = (h16)v.y; h.z = (h16)v.z; h.w = (h16)v.w;
            reinterpret_cast<h16x4*>(x16)[i] = h;
        }
    }
}

// ---------------- scan: unpack cnt, dinv, 3-phase ----------------
__global__ __launch_bounds__(256) void k_scan1(const unsigned long long* __restrict__ packed,
                                               int* __restrict__ rowptr,
                                               int* __restrict__ partials,
                                               float* __restrict__ dinv, int n) {
    __shared__ int wtot[4];
    const int tid = threadIdx.x, lane = tid & 63, wid = tid >> 6;
    int i = blockIdx.x * 256 + tid;
    int v = 0;
    if (i < n) {
        unsigned long long p = packed[i];
        v = (int)(p >> 40);
        float deg = 1.0f + (float)(p & 0xFFFFFFFFFFull) * (1.0f / 1048576.0f);
        dinv[i] = rsqrtf(deg);
    }
    int incl = v;
#pragma unroll
    for (int off = 1; off < 64; off <<= 1) {
        int t = __shfl_up(incl, off, 64);
        if (lane >= off) incl += t;
    }
    if (lane == 63) wtot[wid] = incl;
    __syncthreads();
    int woff = 0;
    for (int k = 0; k < wid; ++k) woff += wtot[k];
    if (i < n) rowptr[i] = woff + incl - v;
    if (tid == 255) partials[blockIdx.x] = woff + incl;
}

__global__ __launch_bounds__(512) void k_scan2(int* __restrict__ partials, int nb) {
    __shared__ int wtot[8];
    const int tid = threadIdx.x, lane = tid & 63, wid = tid >> 6;
    int v = (tid < nb) ? partials[tid] : 0;
    int incl = v;
#pragma unroll
    for (int off = 1; off < 64; off <<= 1) {
        int t = __shfl_up(incl, off, 64);
        if (lane >= off) incl += t;
    }
    if (lane == 63) wtot[wid] = incl;
    __syncthreads();
    int woff = 0;
    for (int k = 0; k < wid; ++k) woff += wtot[k];
    if (tid < nb) partials[tid] = woff + incl - v;
}

__global__ __launch_bounds__(256) void k_scan3(int* __restrict__ rowptr,
                                               const int* __restrict__ partials, int n) {
    int i = blockIdx.x * 256 + threadIdx.x;
    if (i < n) rowptr[i] += partials[blockIdx.x];
    if (blockIdx.x == 0 && threadIdx.x == 0) rowptr[n] = EDGES;
}

// ---------------- CSR build: atomic-free, packed 4B meta = (row<<15)|fp16(w) ----------------
__global__ __launch_bounds__(256) void k_build(const int* __restrict__ rowptr,
                                               const unsigned short* __restrict__ rank,
                                               unsigned* __restrict__ meta,
                                               const int* __restrict__ row, const int* __restrict__ col,
                                               const float* __restrict__ ew,
                                               const float* __restrict__ dinv, int e) {
    int i = blockIdx.x * 256 + threadIdx.x;
    if (i >= e) return;
    int r = row[i], c = col[i];
    float w = dinv[r] * ew[i] * dinv[c];     // w >= 0 always
    unsigned short wb = __builtin_bit_cast(unsigned short, (h16)w);
    meta[rowptr[c] + rank[i]] = ((unsigned)r << 15) | wb;
}

// ---------------- gather agg(x16) 128ch: half-wave pairing, 4ch/lane ----------------
__global__ __launch_bounds__(256) void k_gather_x(h16* __restrict__ Xa,
                                                  const h16* __restrict__ x16,
                                                  const float* __restrict__ dinv,
                                                  const int* __restrict__ rowptr,
                                                  const unsigned* __restrict__ meta, int n) {
    int node = (blockIdx.x << 2) + (threadIdx.x >> 6);
    if (node >= n) return;
    const int lane = threadIdx.x & 63;
    const int half = lane >> 5;
    const int cb = (lane & 31) << 2;
    float a0[4] = {}, a1[4] = {};
    int p = rowptr[node];
    const int end = rowptr[node + 1];
    for (; p + 3 < end; p += 4) {
        unsigned m0 = meta[p + half], m1 = meta[p + half + 2];
        h16x4 h0 = *(const h16x4*)(x16 + (size_t)(m0 >> 15) * 128 + cb);
        h16x4 h1 = *(const h16x4*)(x16 + (size_t)(m1 >> 15) * 128 + cb);
        float w0 = meta_w(m0), w1 = meta_w(m1);
#pragma unroll
        for (int j = 0; j < 4; ++j) {
            a0[j] = fmaf((float)h0[j], w0, a0[j]);
            a1[j] = fmaf((float)h1[j], w1, a1[j]);
        }
    }
    for (; p + 1 < end; p += 2) {
        unsigned m0 = meta[p + half];
        h16x4 h0 = *(const h16x4*)(x16 + (size_t)(m0 >> 15) * 128 + cb);
        float w0 = meta_w(m0);
#pragma unroll
        for (int j = 0; j < 4; ++j) a0[j] = fmaf((float)h0[j], w0, a0[j]);
    }
    if (half == 0 && p < end) {
        unsigned m0 = meta[p];
        h16x4 h0 = *(const h16x4*)(x16 + (size_t)(m0 >> 15) * 128 + cb);
        float w0 = meta_w(m0);
#pragma unroll
        for (int j = 0; j < 4; ++j) a1[j] = fmaf((float)h0[j], w0, a1[j]);
    }
#pragma unroll
    for (int j = 0; j < 4; ++j) a0[j] += a1[j];
#pragma unroll
    for (int j = 0; j < 4; ++j) a0[j] += __shfl(a0[j], lane + 32);
    if (half == 0) {
        float s = dinv[node]; s = s * s;
        h16x4 sv = *(const h16x4*)(x16 + (size_t)node * 128 + cb);
        h16x4 o;
#pragma unroll
        for (int j = 0; j < 4; ++j) o[j] = (h16)fmaf((float)sv[j], s, a0[j]);
        *(h16x4*)(Xa + (size_t)node * 128 + cb) = o;
    }
}

// ---------------- gather Y = agg(P1relu) 256ch: half-wave pairing, 8ch/lane ----------------
__global__ __launch_bounds__(256) void k_gather_y(h16* __restrict__ Y,
                                                  const h16* __restrict__ P1,
                                                  const float* __restrict__ dinv,
                                                  const int* __restrict__ rowptr,
                                                  const unsigned* __restrict__ meta, int n) {
    int node = (blockIdx.x << 2) + (threadIdx.x >> 6);
    if (node >= n) return;
    const int lane = threadIdx.x & 63;
    const int half = lane >> 5;
    const int cb = (lane & 31) << 3;
    float a0[8] = {}, a1[8] = {};
    int p = rowptr[node];
    const int end = rowptr[node + 1];
    for (; p + 3 < end; p += 4) {
        unsigned m0 = meta[p + half], m1 = meta[p + half + 2];
        h16x8 h0 = *(const h16x8*)(P1 + (size_t)(m0 >> 15) * 256 + cb);
        h16x8 h1 = *(const h16x8*)(P1 + (size_t)(m1 >> 15) * 256 + cb);
        float w0 = meta_w(m0), w1 = meta_w(m1);
#pragma unroll
        for (int j = 0; j < 8; ++j) {
            a0[j] = fmaf((float)h0[j], w0, a0[j]);
            a1[j] = fmaf((float)h1[j], w1, a1[j]);
        }
    }
    for (; p + 1 < end; p += 2) {
        unsigned m0 = meta[p + half];
        h16x8 h0 = *(const h16x8*)(P1 + (size_t)(m0 >> 15) * 256 + cb);
        float w0 = meta_w(m0);
#pragma unroll
        for (int j = 0; j < 8; ++j) a0[j] = fmaf((float)h0[j], w0, a0[j]);
    }
    if (half == 0 && p < end) {
        unsigned m0 = meta[p];
        h16x8 h0 = *(const h16x8*)(P1 + (size_t)(m0 >> 15) * 256 + cb);
        float w0 = meta_w(m0);
#pragma unroll
        for (int j = 0; j < 8; ++j) a1[j] = fmaf((float)h0[j], w0, a1[j]);
    }
#pragma unroll
    for (int j = 0; j < 8; ++j) a0[j] += a1[j];
#pragma unroll
    for (int j = 0; j < 8; ++j) a0[j] += __shfl(a0[j], lane + 32);
    if (half == 0) {
        float s = dinv[node]; s = s * s;
        h16x8 sv = *(const h16x8*)(P1 + (size_t)node * 256 + cb);
        h16x8 o;
#pragma unroll
        for (int j = 0; j < 8; ++j) o[j] = (h16)fmaf((float)sv[j], s, a0[j]);
        *(h16x8*)(Y + (size_t)node * 256 + cb) = o;
    }
}

// ---------------- GEMM1: P1relu[M,256] = relu(Xa[M,128] @ (W1h+W1l)^T/64 + b1), fp16 out ----------------
__global__ __launch_bounds__(256) void k_gemm1(const h16* __restrict__ Ag,
                                               const h16* __restrict__ Bhg,
                                               const h16* __restrict__ Blg,
                                               h16* __restrict__ Out,
                                               const float* __restrict__ bias,
                                               int M, int K) {
    __shared__ __attribute__((aligned(16))) char ldsA[8192];
    __shared__ __attribute__((aligned(16))) char ldsBh[8192];
    __shared__ __attribute__((aligned(16))) char ldsBl[8192];
    const int tid = threadIdx.x;
    const int lane = tid & 63, wid = tid >> 6;
    const int quad = lane >> 4, l16 = lane & 15;
    const int rowBase = blockIdx.x * 128;
    const int colBase = blockIdx.y * 128;
    const int wm = (wid & 1) * 64, wn = (wid >> 1) * 64;

    floatx4 acc[4][4] = {};

    const int c0 = wid * 64 + lane;
    const int c1 = c0 + 256;
    const int r0 = ((c0 >> 6) << 4) + (c0 & 15), q0 = (c0 >> 4) & 3;
    const int r1 = ((c1 >> 6) << 4) + (c1 & 15), q1 = (c1 >> 4) & 3;
    const size_t aoff0 = (size_t)(rowBase + r0) * K + q0 * 8;
    const size_t aoff1 = (size_t)(rowBase + r1) * K + q1 * 8;
    const size_t boff0 = (size_t)(colBase + r0) * K + q0 * 8;
    const size_t boff1 = (size_t)(colBase + r1) * K + q1 * 8;
    const int lo0 = (wid * 64) * 16;
    const int lo1 = (256 + wid * 64) * 16;

    for (int k0 = 0; k0 < K; k0 += 32) {
        load_lds16(ldsA + lo0, Ag + aoff0 + k0);
        load_lds16(ldsA + lo1, Ag + aoff1 + k0);
        load_lds16(ldsBh + lo0, Bhg + boff0 + k0);
        load_lds16(ldsBh + lo1, Bhg + boff1 + k0);
        load_lds16(ldsBl + lo0, Blg + boff0 + k0);
        load_lds16(ldsBl + lo1, Blg + boff1 + k0);
        __syncthreads();

        const half8* vA  = (const half8*)ldsA;
        const half8* vBh = (const half8*)ldsBh;
        const half8* vBl = (const half8*)ldsBl;
        half8 af[4], bfh[4], bfl[4];
#pragma unroll
        for (int mi = 0; mi < 4; ++mi)
            af[mi] = vA[((wm >> 4) + mi) * 64 + quad * 16 + l16];
#pragma unroll
        for (int ni = 0; ni < 4; ++ni) {
            int idx = ((wn >> 4) + ni) * 64 + quad * 16 + l16;
            bfh[ni] = vBh[idx];
            bfl[ni] = vBl[idx];
        }
#pragma unroll
        for (int mi = 0; mi < 4; ++mi)
#pragma unroll
            for (int ni = 0; ni < 4; ++ni) {
                acc[mi][ni] = __builtin_amdgcn_mfma_f32_16x16x32_f16(af[mi], bfh[ni], acc[mi][ni], 0, 0, 0);
                acc[mi][ni] = __builtin_amdgcn_mfma_f32_16x16x32_f16(af[mi], bfl[ni], acc[mi][ni], 0, 0, 0);
            }
        __syncthreads();
    }

#pragma unroll
    for (int mi = 0; mi < 4; ++mi) {
#pragma unroll
        for (int r = 0; r < 4; ++r) {
            int grow = rowBase + wm + mi * 16 + quad * 4 + r;
            if (grow < M) {
#pragma unroll
                for (int ni = 0; ni < 4; ++ni) {
                    int gcol = colBase + wn + ni * 16 + l16;
                    float v = fmaxf(acc[mi][ni][r] * WINV + bias[gcol], 0.f);
                    Out[(size_t)grow * 256 + gcol] = (h16)v;
                }
            }
        }
    }
}

// ---------------- fused GEMM2 + FC ----------------
// P2 = relu(Y[M,256] @ (W2h+W2l)^T/64 + b2) held in LDS; out = P2 @ fcW + fcb
__global__ __launch_bounds__(256, 2) void k_gemm2fc(const h16* __restrict__ Y,
                                                    const h16* __restrict__ Bhg,
                                                    const h16* __restrict__ Blg,
                                                    const float* __restrict__ b2,
                                                    const float* __restrict__ fcW,
                                                    const float* __restrict__ fcb,
                                                    float* __restrict__ out, int M) {
    __shared__ __attribute__((aligned(16))) char lds[67584];   // union: staging 40KB / P2s 128x264 fp16
    char* ldsA  = lds;
    char* ldsBh = lds + 8192;
    char* ldsBl = lds + 24576;
    const int tid = threadIdx.x;
    const int lane = tid & 63, wid = tid >> 6;
    const int quad = lane >> 4, l16 = lane & 15;
    const int rowBase = blockIdx.x * 128;
    const int wm = (wid & 1) * 64, wn = (wid >> 1) * 128;

    floatx4 acc[4][8] = {};

    for (int k0 = 0; k0 < 256; k0 += 32) {
#pragma unroll
        for (int i = 0; i < 2; ++i) {
            int c = tid + i * 256;
            int r = ((c >> 6) << 4) + (c & 15), q = (c >> 4) & 3;
            load_lds16(ldsA + c * 16, Y + (size_t)(rowBase + r) * 256 + k0 + q * 8);
        }
#pragma unroll
        for (int i = 0; i < 4; ++i) {
            int c = tid + i * 256;
            int r = ((c >> 6) << 4) + (c & 15), q = (c >> 4) & 3;
            size_t go = (size_t)r * 256 + k0 + q * 8;
            load_lds16(ldsBh + c * 16, Bhg + go);
            load_lds16(ldsBl + c * 16, Blg + go);
        }
        __syncthreads();

        const half8* vA  = (const half8*)ldsA;
        const half8* vBh = (const half8*)ldsBh;
        const half8* vBl = (const half8*)ldsBl;
        half8 af[4];
#pragma unroll
        for (int mi = 0; mi < 4; ++mi)
            af[mi] = vA[((wm >> 4) + mi) * 64 + quad * 16 + l16];
#pragma unroll
        for (int ni = 0; ni < 8; ++ni) {
            int bidx = ((wn >> 4) + ni) * 64 + quad * 16 + l16;
            half8 bh = vBh[bidx];
            half8 bl = vBl[bidx];
#pragma unroll
            for (int mi = 0; mi < 4; ++mi) {
                acc[mi][ni] = __builtin_amdgcn_mfma_f32_16x16x32_f16(af[mi], bh, acc[mi][ni], 0, 0, 0);
                acc[mi][ni] = __builtin_amdgcn_mfma_f32_16x16x32_f16(af[mi], bl, acc[mi][ni], 0, 0, 0);
            }
        }
        __syncthreads();
    }

    // epilogue: P2s[128][264] fp16 in LDS (stride 264 keeps 16B alignment, 2-way banks)
    h16* P2s = (h16*)lds;
#pragma unroll
    for (int mi = 0; mi < 4; ++mi)
#pragma unroll
        for (int r = 0; r < 4; ++r) {
            int lrow = wm + mi * 16 + quad * 4 + r;
#pragma unroll
            for (int ni = 0; ni < 8; ++ni) {
                int col = wn + ni * 16 + l16;
                float v = fmaxf(acc[mi][ni][r] * WINV + b2[col], 0.f);
                P2s[lrow * 264 + col] = (h16)v;
            }
        }
    __syncthreads();

    // FC: wave (wid&1) -> row half, (wid>>1) -> 20-col half; fcW reads are wave-uniform (scalar)
    const int myrow = (wid & 1) * 64 + lane;
    const int jb = (wid >> 1) * 20;
    const int grow = rowBase + myrow;
    float fa[20] = {};
    for (int kc = 0; kc < 32; ++kc) {
        h16x8 xv8 = *(const h16x8*)(P2s + myrow * 264 + kc * 8);
        float xv[8];
#pragma unroll
        for (int j = 0; j < 8; ++j) xv[j] = (float)xv8[j];
#pragma unroll
        for (int kk = 0; kk < 8; ++kk) {
            const float* wrow = fcW + (kc * 8 + kk) * 40 + jb;
#pragma unroll
            for (int j = 0; j < 20; ++j)
                fa[j] = fmaf(xv[kk], wrow[j], fa[j]);
        }
    }
    if (grow < M) {
#pragma unroll
        for (int j = 0; j < 20; ++j)
            out[(size_t)grow * 40 + jb + j] = fa[j] + fcb[jb + j];
    }
}

extern "C" void kernel_launch(void* const* d_in, const int* in_sizes, int n_in,
                              void* d_out, int out_size, void* d_ws, size_t ws_size,
                              hipStream_t stream) {
    const float* x   = (const float*)d_in[0];
    const int*   ei  = (const int*)d_in[1];
    const float* ea  = (const float*)d_in[2];
    const float* W1  = (const float*)d_in[3];
    const float* b1  = (const float*)d_in[4];
    const float* W2  = (const float*)d_in[5];
    const float* b2  = (const float*)d_in[6];
    const float* fcW = (const float*)d_in[7];
    const float* fcb = (const float*)d_in[8];
    float* out = (float*)d_out;

    const int n = NODES, e = EDGES;
    const int* row = ei;
    const int* col = ei + e;

    char* ws = (char*)d_ws;
    char*  Areg   = ws;                                        // 102,400,000 B
    char*  Breg   = ws + 102400000u;                           // 102,400,000 B
    float* dinv   = (float*)(ws + 204800000u);                 // 400,000 B
    unsigned long long* packed = (unsigned long long*)(ws + 205200000u); // 800,000 B
    int*   rowptr = (int*)  (ws + 206000000u);                 // 400,016 B
    unsigned* meta = (unsigned*)(ws + 206400016u);             // 6,400,000 B -> 212,800,016
    h16*   W1h    = (h16*)  (ws + 212800016u);                 // 65,536 B
    h16*   W1l    = (h16*)  (ws + 212865552u);                 // 65,536 B
    h16*   W2h    = (h16*)  (ws + 212931088u);                 // 131,072 B
    h16*   W2l    = (h16*)  (ws + 213062160u);                 // 131,072 B -> 213,193,232

    // overlays (time-shared):
    int* partials = (int*)Areg;                                // scan temp (dies after scan3)
    h16* Xa16 = (h16*)Areg;                                    // 25.6 MB agg(x) [after scan3]
    h16* x16  = (h16*)(Areg + 25600000u);                      // 25.6 MB fp16 x
    h16* Yh   = (h16*)Areg;                                    // 51.2 MB Y = agg(P1relu) [after gemm1]
    unsigned short* rank = (unsigned short*)Breg;              // 3.2 MB (dies after build)
    h16* P1   = (h16*)Breg;                                    // 51.2 MB relu(P1) fp16 [after build]

    const int nb = (n + 255) / 256;   // 391
    const int eb = e / 256;           // 6250

    // ---- CSR build + fused conversions ----
    k_init<<<nb, 256, 0, stream>>>(packed, n);
    k_hist<<<19134, 256, 0, stream>>>(packed, rank, col, ea, e,
                                      W1, W1h, W1l, W2, W2h, W2l, x, x16, n);
    k_scan1<<<nb, 256, 0, stream>>>(packed, rowptr, partials, dinv, n);
    k_scan2<<<1, 512, 0, stream>>>(partials, nb);
    k_scan3<<<nb, 256, 0, stream>>>(rowptr, partials, n);
    k_build<<<eb, 256, 0, stream>>>(rowptr, rank, meta, row, col, ea, dinv, e);

    // layer 1 (agg-first): Xa = agg(x16) ; P1 = relu(Xa@W1 + b1) fp16
    k_gather_x<<<(n + 3) / 4, 256, 0, stream>>>(Xa16, x16, dinv, rowptr, meta, n);
    dim3 gg((n + 127) / 128, 2);
    k_gemm1<<<gg, 256, 0, stream>>>(Xa16, W1h, W1l, P1, b1, n, 128);

    // layer 2 (agg-first): Y = agg(P1) ; out = relu(Y@W2 + b2) @ fcW + fcb  (fused)
    k_gather_y<<<(n + 3) / 4, 256, 0, stream>>>(Yh, P1, dinv, rowptr, meta, n);
    k_gemm2fc<<<(n + 127) / 128, 256, 0, stream>>>(Yh, W2h, W2l, b2, fcW, fcb, out, n);
}

// Round 11
// 612.205 us; speedup vs baseline: 1.0853x; 1.0853x over previous
//
#include <hip/hip_runtime.h>

#define NODES 100000
#define EDGES 1600000

typedef __attribute__((ext_vector_type(4))) float floatx4;
typedef _Float16 h16;
typedef __attribute__((ext_vector_type(4))) _Float16 h16x4;
typedef __attribute__((ext_vector_type(8))) _Float16 h16x8;
typedef __attribute__((ext_vector_type(8))) _Float16 half8;

#define WSCALE 64.0f
#define WINV   (1.0f / 64.0f)

__device__ inline void load_lds16(void* lds, const void* g) {
    __builtin_amdgcn_global_load_lds((const __attribute__((address_space(1))) void*)g,
                                     (__attribute__((address_space(3))) void*)lds, 16, 0, 0);
}

__device__ inline float meta_w(unsigned m) {
    return (float)__builtin_bit_cast(h16, (unsigned short)(m & 0x7FFFu));
}

// ---------------- init packed accumulator ----------------
__global__ __launch_bounds__(256) void k_init(unsigned long long* __restrict__ packed, int n) {
    int i = blockIdx.x * 256 + threadIdx.x;
    if (i < n) packed[i] = 0ull;
}

// ---------------- fused: histogram+rank | W1 split | W2 split | x->fp16 ----------------
__device__ inline void w_split(const float* W, h16* Wh, h16* Wl, int idx, int K) {
    int k = idx >> 8, nn = idx & 255;
    float v = W[idx] * WSCALE;
    h16 h = (h16)v;
    h16 l = (h16)(v - (float)h);
    Wh[nn * K + k] = h;
    Wl[nn * K + k] = l;
}

__global__ __launch_bounds__(256) void k_hist(unsigned long long* __restrict__ packed,
                                              unsigned short* __restrict__ rank,
                                              const int* __restrict__ col,
                                              const float* __restrict__ ew, int e,
                                              const float* __restrict__ W1, h16* __restrict__ W1h, h16* __restrict__ W1l,
                                              const float* __restrict__ W2, h16* __restrict__ W2h, h16* __restrict__ W2l,
                                              const float* __restrict__ x, h16* __restrict__ x16, int n) {
    int b = blockIdx.x;
    if (b < 6250) {
        int i = b * 256 + threadIdx.x;
        if (i < e) {
            int c = col[i];
            unsigned long long v = (1ull << 40) |
                (unsigned long long)__float2uint_rn(ew[i] * 1048576.0f);
            unsigned long long old = atomicAdd(&packed[c], v);
            rank[i] = (unsigned short)(old >> 40);
        }
    } else if (b < 6378) {
        w_split(W1, W1h, W1l, (b - 6250) * 256 + threadIdx.x, 128);
    } else if (b < 6634) {
        w_split(W2, W2h, W2l, (b - 6378) * 256 + threadIdx.x, 256);
    } else {
        int i = (b - 6634) * 256 + threadIdx.x;
        if (i < n * 32) {
            float4 v = reinterpret_cast<const float4*>(x)[i];
            h16x4 h;
            h.x = (h16)v.x; h.y = (h16)v.y; h.z = (h16)v.z; h.w = (h16)v.w;
            reinterpret_cast<h16x4*>(x16)[i] = h;
        }
    }
}

// ---------------- scan: unpack cnt, dinv, 3-phase ----------------
__global__ __launch_bounds__(256) void k_scan1(const unsigned long long* __restrict__ packed,
                                               int* __restrict__ rowptr,
                                               int* __restrict__ partials,
                                               float* __restrict__ dinv, int n) {
    __shared__ int wtot[4];
    const int tid = threadIdx.x, lane = tid & 63, wid = tid >> 6;
    int i = blockIdx.x * 256 + tid;
    int v = 0;
    if (i < n) {
        unsigned long long p = packed[i];
        v = (int)(p >> 40);
        float deg = 1.0f + (float)(p & 0xFFFFFFFFFFull) * (1.0f / 1048576.0f);
        dinv[i] = rsqrtf(deg);
    }
    int incl = v;
#pragma unroll
    for (int off = 1; off < 64; off <<= 1) {
        int t = __shfl_up(incl, off, 64);
        if (lane >= off) incl += t;
    }
    if (lane == 63) wtot[wid] = incl;
    __syncthreads();
    int woff = 0;
    for (int k = 0; k < wid; ++k) woff += wtot[k];
    if (i < n) rowptr[i] = woff + incl - v;
    if (tid == 255) partials[blockIdx.x] = woff + incl;
}

__global__ __launch_bounds__(512) void k_scan2(int* __restrict__ partials, int nb) {
    __shared__ int wtot[8];
    const int tid = threadIdx.x, lane = tid & 63, wid = tid >> 6;
    int v = (tid < nb) ? partials[tid] : 0;
    int incl = v;
#pragma unroll
    for (int off = 1; off < 64; off <<= 1) {
        int t = __shfl_up(incl, off, 64);
        if (lane >= off) incl += t;
    }
    if (lane == 63) wtot[wid] = incl;
    __syncthreads();
    int woff = 0;
    for (int k = 0; k < wid; ++k) woff += wtot[k];
    if (tid < nb) partials[tid] = woff + incl - v;
}

__global__ __launch_bounds__(256) void k_scan3(int* __restrict__ rowptr,
                                               const int* __restrict__ partials, int n) {
    int i = blockIdx.x * 256 + threadIdx.x;
    if (i < n) rowptr[i] += partials[blockIdx.x];
    if (blockIdx.x == 0 && threadIdx.x == 0) rowptr[n] = EDGES;
}

// ---------------- CSR build: atomic-free, packed 4B meta = (row<<15)|fp16(w) ----------------
__global__ __launch_bounds__(256) void k_build(const int* __restrict__ rowptr,
                                               const unsigned short* __restrict__ rank,
                                               unsigned* __restrict__ meta,
                                               const int* __restrict__ row, const int* __restrict__ col,
                                               const float* __restrict__ ew,
                                               const float* __restrict__ dinv, int e) {
    int i = blockIdx.x * 256 + threadIdx.x;
    if (i >= e) return;
    int r = row[i], c = col[i];
    float w = dinv[r] * ew[i] * dinv[c];     // w >= 0 always
    unsigned short wb = __builtin_bit_cast(unsigned short, (h16)w);
    meta[rowptr[c] + rank[i]] = ((unsigned)r << 15) | wb;
}

// ---------------- gather agg(x16) 128ch: half-wave pairing, 4ch/lane ----------------
__global__ __launch_bounds__(256) void k_gather_x(h16* __restrict__ Xa,
                                                  const h16* __restrict__ x16,
                                                  const float* __restrict__ dinv,
                                                  const int* __restrict__ rowptr,
                                                  const unsigned* __restrict__ meta, int n) {
    int node = (blockIdx.x << 2) + (threadIdx.x >> 6);
    if (node >= n) return;
    const int lane = threadIdx.x & 63;
    const int half = lane >> 5;
    const int cb = (lane & 31) << 2;
    float a0[4] = {}, a1[4] = {};
    int p = rowptr[node];
    const int end = rowptr[node + 1];
    for (; p + 3 < end; p += 4) {
        unsigned m0 = meta[p + half], m1 = meta[p + half + 2];
        h16x4 h0 = *(const h16x4*)(x16 + (size_t)(m0 >> 15) * 128 + cb);
        h16x4 h1 = *(const h16x4*)(x16 + (size_t)(m1 >> 15) * 128 + cb);
        float w0 = meta_w(m0), w1 = meta_w(m1);
#pragma unroll
        for (int j = 0; j < 4; ++j) {
            a0[j] = fmaf((float)h0[j], w0, a0[j]);
            a1[j] = fmaf((float)h1[j], w1, a1[j]);
        }
    }
    for (; p + 1 < end; p += 2) {
        unsigned m0 = meta[p + half];
        h16x4 h0 = *(const h16x4*)(x16 + (size_t)(m0 >> 15) * 128 + cb);
        float w0 = meta_w(m0);
#pragma unroll
        for (int j = 0; j < 4; ++j) a0[j] = fmaf((float)h0[j], w0, a0[j]);
    }
    if (half == 0 && p < end) {
        unsigned m0 = meta[p];
        h16x4 h0 = *(const h16x4*)(x16 + (size_t)(m0 >> 15) * 128 + cb);
        float w0 = meta_w(m0);
#pragma unroll
        for (int j = 0; j < 4; ++j) a1[j] = fmaf((float)h0[j], w0, a1[j]);
    }
#pragma unroll
    for (int j = 0; j < 4; ++j) a0[j] += a1[j];
#pragma unroll
    for (int j = 0; j < 4; ++j) a0[j] += __shfl(a0[j], lane + 32);
    if (half == 0) {
        float s = dinv[node]; s = s * s;
        h16x4 sv = *(const h16x4*)(x16 + (size_t)node * 128 + cb);
        h16x4 o;
#pragma unroll
        for (int j = 0; j < 4; ++j) o[j] = (h16)fmaf((float)sv[j], s, a0[j]);
        *(h16x4*)(Xa + (size_t)node * 128 + cb) = o;
    }
}

// ---------------- gather Y = agg(P1relu) 256ch: half-wave pairing, 8ch/lane ----------------
__global__ __launch_bounds__(256) void k_gather_y(h16* __restrict__ Y,
                                                  const h16* __restrict__ P1,
                                                  const float* __restrict__ dinv,
                                                  const int* __restrict__ rowptr,
                                                  const unsigned* __restrict__ meta, int n) {
    int node = (blockIdx.x << 2) + (threadIdx.x >> 6);
    if (node >= n) return;
    const int lane = threadIdx.x & 63;
    const int half = lane >> 5;
    const int cb = (lane & 31) << 3;
    float a0[8] = {}, a1[8] = {};
    int p = rowptr[node];
    const int end = rowptr[node + 1];
    for (; p + 3 < end; p += 4) {
        unsigned m0 = meta[p + half], m1 = meta[p + half + 2];
        h16x8 h0 = *(const h16x8*)(P1 + (size_t)(m0 >> 15) * 256 + cb);
        h16x8 h1 = *(const h16x8*)(P1 + (size_t)(m1 >> 15) * 256 + cb);
        float w0 = meta_w(m0), w1 = meta_w(m1);
#pragma unroll
        for (int j = 0; j < 8; ++j) {
            a0[j] = fmaf((float)h0[j], w0, a0[j]);
            a1[j] = fmaf((float)h1[j], w1, a1[j]);
        }
    }
    for (; p + 1 < end; p += 2) {
        unsigned m0 = meta[p + half];
        h16x8 h0 = *(const h16x8*)(P1 + (size_t)(m0 >> 15) * 256 + cb);
        float w0 = meta_w(m0);
#pragma unroll
        for (int j = 0; j < 8; ++j) a0[j] = fmaf((float)h0[j], w0, a0[j]);
    }
    if (half == 0 && p < end) {
        unsigned m0 = meta[p];
        h16x8 h0 = *(const h16x8*)(P1 + (size_t)(m0 >> 15) * 256 + cb);
        float w0 = meta_w(m0);
#pragma unroll
        for (int j = 0; j < 8; ++j) a1[j] = fmaf((float)h0[j], w0, a1[j]);
    }
#pragma unroll
    for (int j = 0; j < 8; ++j) a0[j] += a1[j];
#pragma unroll
    for (int j = 0; j < 8; ++j) a0[j] += __shfl(a0[j], lane + 32);
    if (half == 0) {
        float s = dinv[node]; s = s * s;
        h16x8 sv = *(const h16x8*)(P1 + (size_t)node * 256 + cb);
        h16x8 o;
#pragma unroll
        for (int j = 0; j < 8; ++j) o[j] = (h16)fmaf((float)sv[j], s, a0[j]);
        *(h16x8*)(Y + (size_t)node * 256 + cb) = o;
    }
}

// ---------------- fp16 2-product MFMA GEMM: Out = relu(A @ (Wh+Wl)^T/64 + b), fp16 ----------------
// A [M,K] fp16, Wh/Wl [256,K] fp16 (x64). 128x128 tile, 16KB-class LDS, 4 waves.
__global__ __launch_bounds__(256) void k_gemm(const h16* __restrict__ Ag,
                                              const h16* __restrict__ Bhg,
                                              const h16* __restrict__ Blg,
                                              h16* __restrict__ Out,
                                              const float* __restrict__ bias,
                                              int M, int K) {
    __shared__ __attribute__((aligned(16))) char ldsA[8192];
    __shared__ __attribute__((aligned(16))) char ldsBh[8192];
    __shared__ __attribute__((aligned(16))) char ldsBl[8192];
    const int tid = threadIdx.x;
    const int lane = tid & 63, wid = tid >> 6;
    const int quad = lane >> 4, l16 = lane & 15;
    const int rowBase = blockIdx.x * 128;
    const int colBase = blockIdx.y * 128;
    const int wm = (wid & 1) * 64, wn = (wid >> 1) * 64;

    floatx4 acc[4][4] = {};

    const int c0 = wid * 64 + lane;
    const int c1 = c0 + 256;
    const int r0 = ((c0 >> 6) << 4) + (c0 & 15), q0 = (c0 >> 4) & 3;
    const int r1 = ((c1 >> 6) << 4) + (c1 & 15), q1 = (c1 >> 4) & 3;
    const size_t aoff0 = (size_t)(rowBase + r0) * K + q0 * 8;
    const size_t aoff1 = (size_t)(rowBase + r1) * K + q1 * 8;
    const size_t boff0 = (size_t)(colBase + r0) * K + q0 * 8;
    const size_t boff1 = (size_t)(colBase + r1) * K + q1 * 8;
    const int lo0 = (wid * 64) * 16;
    const int lo1 = (256 + wid * 64) * 16;

    for (int k0 = 0; k0 < K; k0 += 32) {
        load_lds16(ldsA + lo0, Ag + aoff0 + k0);
        load_lds16(ldsA + lo1, Ag + aoff1 + k0);
        load_lds16(ldsBh + lo0, Bhg + boff0 + k0);
        load_lds16(ldsBh + lo1, Bhg + boff1 + k0);
        load_lds16(ldsBl + lo0, Blg + boff0 + k0);
        load_lds16(ldsBl + lo1, Blg + boff1 + k0);
        __syncthreads();

        const half8* vA  = (const half8*)ldsA;
        const half8* vBh = (const half8*)ldsBh;
        const half8* vBl = (const half8*)ldsBl;
        half8 af[4], bfh[4], bfl[4];
#pragma unroll
        for (int mi = 0; mi < 4; ++mi)
            af[mi] = vA[((wm >> 4) + mi) * 64 + quad * 16 + l16];
#pragma unroll
        for (int ni = 0; ni < 4; ++ni) {
            int idx = ((wn >> 4) + ni) * 64 + quad * 16 + l16;
            bfh[ni] = vBh[idx];
            bfl[ni] = vBl[idx];
        }
#pragma unroll
        for (int mi = 0; mi < 4; ++mi)
#pragma unroll
            for (int ni = 0; ni < 4; ++ni) {
                acc[mi][ni] = __builtin_amdgcn_mfma_f32_16x16x32_f16(af[mi], bfh[ni], acc[mi][ni], 0, 0, 0);
                acc[mi][ni] = __builtin_amdgcn_mfma_f32_16x16x32_f16(af[mi], bfl[ni], acc[mi][ni], 0, 0, 0);
            }
        __syncthreads();
    }

#pragma unroll
    for (int mi = 0; mi < 4; ++mi) {
#pragma unroll
        for (int r = 0; r < 4; ++r) {
            int grow = rowBase + wm + mi * 16 + quad * 4 + r;
            if (grow < M) {
#pragma unroll
                for (int ni = 0; ni < 4; ++ni) {
                    int gcol = colBase + wn + ni * 16 + l16;
                    float v = fmaxf(acc[mi][ni][r] * WINV + bias[gcol], 0.f);
                    Out[(size_t)grow * 256 + gcol] = (h16)v;
                }
            }
        }
    }
}

// ---------------- FC: out[M,40] = X16[M,256] @ W[256,40] + b  (X16 already relu'd fp16) ----------------
__global__ __launch_bounds__(256) void k_fc(float* __restrict__ out, const h16* __restrict__ X,
                                            const float* __restrict__ W, const float* __restrict__ bias,
                                            int M) {
    __shared__ float Ws[256 * 40];
    __shared__ float Xs[32][69];
    const int tid = threadIdx.x;
#pragma unroll
    for (int t = 0; t < 10; ++t) {
        int idx = (t * 256 + tid) * 4;
        *reinterpret_cast<float4*>(&Ws[idx]) = *reinterpret_cast<const float4*>(W + idx);
    }
    const int rowBase = blockIdx.x * 64;
    const int r  = tid >> 2;
    const int cg = (tid & 3) * 10;
    const int kq = (tid & 3) << 3;
    float acc[10] = {};

    for (int k0 = 0; k0 < 256; k0 += 32) {
        int rr = rowBase + r;
        h16x8 v = {};
        if (rr < M) v = *reinterpret_cast<const h16x8*>(X + (size_t)rr * 256 + k0 + kq);
#pragma unroll
        for (int j = 0; j < 8; ++j) Xs[kq + j][r] = (float)v[j];
        __syncthreads();
#pragma unroll
        for (int kk = 0; kk < 32; ++kk) {
            float xv = Xs[kk][r];
#pragma unroll
            for (int j = 0; j < 10; ++j)
                acc[j] = fmaf(xv, Ws[(k0 + kk) * 40 + cg + j], acc[j]);
        }
        __syncthreads();
    }

    int orow = rowBase + r;
    if (orow < M) {
#pragma unroll
        for (int j = 0; j < 10; ++j)
            out[(size_t)orow * 40 + cg + j] = acc[j] + bias[cg + j];
    }
}

extern "C" void kernel_launch(void* const* d_in, const int* in_sizes, int n_in,
                              void* d_out, int out_size, void* d_ws, size_t ws_size,
                              hipStream_t stream) {
    const float* x   = (const float*)d_in[0];
    const int*   ei  = (const int*)d_in[1];
    const float* ea  = (const float*)d_in[2];
    const float* W1  = (const float*)d_in[3];
    const float* b1  = (const float*)d_in[4];
    const float* W2  = (const float*)d_in[5];
    const float* b2  = (const float*)d_in[6];
    const float* fcW = (const float*)d_in[7];
    const float* fcb = (const float*)d_in[8];
    float* out = (float*)d_out;

    const int n = NODES, e = EDGES;
    const int* row = ei;
    const int* col = ei + e;

    char* ws = (char*)d_ws;
    char*  Areg   = ws;                                        // 102,400,000 B
    char*  Breg   = ws + 102400000u;                           // 102,400,000 B
    float* dinv   = (float*)(ws + 204800000u);                 // 400,000 B
    unsigned long long* packed = (unsigned long long*)(ws + 205200000u); // 800,000 B
    int*   rowptr = (int*)  (ws + 206000000u);                 // 400,016 B
    unsigned* meta = (unsigned*)(ws + 206400016u);             // 6,400,000 B -> 212,800,016
    h16*   W1h    = (h16*)  (ws + 212800016u);                 // 65,536 B
    h16*   W1l    = (h16*)  (ws + 212865552u);                 // 65,536 B
    h16*   W2h    = (h16*)  (ws + 212931088u);                 // 131,072 B
    h16*   W2l    = (h16*)  (ws + 213062160u);                 // 131,072 B -> 213,193,232

    // overlays (time-shared):
    int* partials = (int*)Areg;                                // scan temp (dies after scan3)
    h16* Xa16 = (h16*)Areg;                                    // 25.6 MB agg(x) [after scan3]
    h16* x16  = (h16*)(Areg + 25600000u);                      // 25.6 MB fp16 x
    h16* Yh   = (h16*)Areg;                                    // 51.2 MB Y = agg(P1relu) [after gemm1]
    unsigned short* rank = (unsigned short*)Breg;              // 3.2 MB (dies after build)
    h16* P1   = (h16*)Breg;                                    // 51.2 MB relu(P1) fp16 [after build]
    h16* P2h  = (h16*)(Breg + 51200000u);                      // 51.2 MB relu(P2) fp16 [gemm2 out]

    const int nb = (n + 255) / 256;   // 391
    const int eb = e / 256;           // 6250

    // ---- CSR build + fused conversions ----
    k_init<<<nb, 256, 0, stream>>>(packed, n);
    k_hist<<<19134, 256, 0, stream>>>(packed, rank, col, ea, e,
                                      W1, W1h, W1l, W2, W2h, W2l, x, x16, n);
    k_scan1<<<nb, 256, 0, stream>>>(packed, rowptr, partials, dinv, n);
    k_scan2<<<1, 512, 0, stream>>>(partials, nb);
    k_scan3<<<nb, 256, 0, stream>>>(rowptr, partials, n);
    k_build<<<eb, 256, 0, stream>>>(rowptr, rank, meta, row, col, ea, dinv, e);

    dim3 gg((n + 127) / 128, 2);

    // layer 1 (agg-first): Xa = agg(x16) ; P1 = relu(Xa@W1 + b1) fp16
    k_gather_x<<<(n + 3) / 4, 256, 0, stream>>>(Xa16, x16, dinv, rowptr, meta, n);
    k_gemm<<<gg, 256, 0, stream>>>(Xa16, W1h, W1l, P1, b1, n, 128);

    // layer 2 (agg-first): Y = agg(P1) ; P2 = relu(Y@W2 + b2) fp16
    k_gather_y<<<(n + 3) / 4, 256, 0, stream>>>(Yh, P1, dinv, rowptr, meta, n);
    k_gemm<<<gg, 256, 0, stream>>>(Yh, W2h, W2l, P2h, b2, n, 256);

    // classifier
    k_fc<<<(n + 63) / 64, 256, 0, stream>>>(out, P2h, fcW, fcb, n);
}

// Round 12
// 555.967 us; speedup vs baseline: 1.1951x; 1.1012x over previous
//
#include <hip/hip_runtime.h>

#define NODES 100000
#define EDGES 1600000

typedef __attribute__((ext_vector_type(4))) float floatx4;
typedef _Float16 h16;
typedef __attribute__((ext_vector_type(4))) _Float16 h16x4;
typedef __attribute__((ext_vector_type(8))) _Float16 h16x8;
typedef __attribute__((ext_vector_type(8))) _Float16 half8;

#define WSCALE 64.0f
#define WINV   (1.0f / 64.0f)

__device__ inline void load_lds16(void* lds, const void* g) {
    __builtin_amdgcn_global_load_lds((const __attribute__((address_space(1))) void*)g,
                                     (__attribute__((address_space(3))) void*)lds, 16, 0, 0);
}

__device__ inline float meta_w(unsigned m) {
    return (float)__builtin_bit_cast(h16, (unsigned short)(m & 0x7FFFu));
}

// ---------------- init packed accumulator ----------------
__global__ __launch_bounds__(256) void k_init(unsigned long long* __restrict__ packed, int n) {
    int i = blockIdx.x * 256 + threadIdx.x;
    if (i < n) packed[i] = 0ull;
}

// ---------------- fused: histogram+rank | W1 split | W2 split | x->fp16 ----------------
__device__ inline void w_split(const float* W, h16* Wh, h16* Wl, int idx, int K) {
    int k = idx >> 8, nn = idx & 255;
    float v = W[idx] * WSCALE;
    h16 h = (h16)v;
    h16 l = (h16)(v - (float)h);
    Wh[nn * K + k] = h;
    Wl[nn * K + k] = l;
}

__global__ __launch_bounds__(256) void k_hist(unsigned long long* __restrict__ packed,
                                              unsigned short* __restrict__ rank,
                                              const int* __restrict__ col,
                                              const float* __restrict__ ew, int e,
                                              const float* __restrict__ W1, h16* __restrict__ W1h, h16* __restrict__ W1l,
                                              const float* __restrict__ W2, h16* __restrict__ W2h, h16* __restrict__ W2l,
                                              const float* __restrict__ x, h16* __restrict__ x16, int n) {
    int b = blockIdx.x;
    if (b < 6250) {
        int i = b * 256 + threadIdx.x;
        if (i < e) {
            int c = col[i];
            unsigned long long v = (1ull << 40) |
                (unsigned long long)__float2uint_rn(ew[i] * 1048576.0f);
            unsigned long long old = atomicAdd(&packed[c], v);
            rank[i] = (unsigned short)(old >> 40);
        }
    } else if (b < 6378) {
        w_split(W1, W1h, W1l, (b - 6250) * 256 + threadIdx.x, 128);
    } else if (b < 6634) {
        w_split(W2, W2h, W2l, (b - 6378) * 256 + threadIdx.x, 256);
    } else {
        int i = (b - 6634) * 256 + threadIdx.x;
        if (i < n * 32) {
            float4 v = reinterpret_cast<const float4*>(x)[i];
            h16x4 h;
            h.x = (h16)v.x; h.y = (h16)v.y; h.z = (h16)v.z; h.w = (h16)v.w;
            reinterpret_cast<h16x4*>(x16)[i] = h;
        }
    }
}

// ---------------- scan phase 1: unpack cnt, dinv, per-block exclusive scan ----------------
__global__ __launch_bounds__(256) void k_scan1(const unsigned long long* __restrict__ packed,
                                               int* __restrict__ rowptr,
                                               int* __restrict__ partials,
                                               float* __restrict__ dinv, int n) {
    __shared__ int wtot[4];
    const int tid = threadIdx.x, lane = tid & 63, wid = tid >> 6;
    int i = blockIdx.x * 256 + tid;
    int v = 0;
    if (i < n) {
        unsigned long long p = packed[i];
        v = (int)(p >> 40);
        float deg = 1.0f + (float)(p & 0xFFFFFFFFFFull) * (1.0f / 1048576.0f);
        dinv[i] = rsqrtf(deg);
    }
    int incl = v;
#pragma unroll
    for (int off = 1; off < 64; off <<= 1) {
        int t = __shfl_up(incl, off, 64);
        if (lane >= off) incl += t;
    }
    if (lane == 63) wtot[wid] = incl;
    __syncthreads();
    int woff = 0;
    for (int k = 0; k < wid; ++k) woff += wtot[k];
    if (i < n) rowptr[i] = woff + incl - v;
    if (tid == 255) partials[blockIdx.x] = woff + incl;
}

// ---------------- scan phase 2+3 fused: each block computes its own prefix base ----------------
__global__ __launch_bounds__(256) void k_scan3(int* __restrict__ rowptr,
                                               const int* __restrict__ partials, int n) {
    __shared__ int wsum[4];
    const int tid = threadIdx.x, lane = tid & 63, wid = tid >> 6;
    const int b = blockIdx.x;
    int v = 0;
    for (int t = tid; t < b; t += 256) v += partials[t];
#pragma unroll
    for (int off = 32; off > 0; off >>= 1) v += __shfl_down(v, off, 64);
    if (lane == 0) wsum[wid] = v;
    __syncthreads();
    int base = wsum[0] + wsum[1] + wsum[2] + wsum[3];
    int i = b * 256 + tid;
    if (i < n) rowptr[i] += base;
    if (b == 0 && tid == 0) rowptr[n] = EDGES;
}

// ---------------- CSR build: atomic-free, packed 4B meta = (row<<15)|fp16(w) ----------------
__global__ __launch_bounds__(256) void k_build(const int* __restrict__ rowptr,
                                               const unsigned short* __restrict__ rank,
                                               unsigned* __restrict__ meta,
                                               const int* __restrict__ row, const int* __restrict__ col,
                                               const float* __restrict__ ew,
                                               const float* __restrict__ dinv, int e) {
    int i = blockIdx.x * 256 + threadIdx.x;
    if (i >= e) return;
    int r = row[i], c = col[i];
    float w = dinv[r] * ew[i] * dinv[c];     // w >= 0 always
    unsigned short wb = __builtin_bit_cast(unsigned short, (h16)w);
    meta[rowptr[c] + rank[i]] = ((unsigned)r << 15) | wb;
}

// ---------------- gather agg(x16) 128ch: half-wave pairing, 4ch/lane ----------------
__global__ __launch_bounds__(256) void k_gather_x(h16* __restrict__ Xa,
                                                  const h16* __restrict__ x16,
                                                  const float* __restrict__ dinv,
                                                  const int* __restrict__ rowptr,
                                                  const unsigned* __restrict__ meta, int n) {
    int node = (blockIdx.x << 2) + (threadIdx.x >> 6);
    if (node >= n) return;
    const int lane = threadIdx.x & 63;
    const int half = lane >> 5;
    const int cb = (lane & 31) << 2;
    float a0[4] = {}, a1[4] = {};
    int p = rowptr[node];
    const int end = rowptr[node + 1];
    for (; p + 3 < end; p += 4) {
        unsigned m0 = meta[p + half], m1 = meta[p + half + 2];
        h16x4 h0 = *(const h16x4*)(x16 + (size_t)(m0 >> 15) * 128 + cb);
        h16x4 h1 = *(const h16x4*)(x16 + (size_t)(m1 >> 15) * 128 + cb);
        float w0 = meta_w(m0), w1 = meta_w(m1);
#pragma unroll
        for (int j = 0; j < 4; ++j) {
            a0[j] = fmaf((float)h0[j], w0, a0[j]);
            a1[j] = fmaf((float)h1[j], w1, a1[j]);
        }
    }
    for (; p + 1 < end; p += 2) {
        unsigned m0 = meta[p + half];
        h16x4 h0 = *(const h16x4*)(x16 + (size_t)(m0 >> 15) * 128 + cb);
        float w0 = meta_w(m0);
#pragma unroll
        for (int j = 0; j < 4; ++j) a0[j] = fmaf((float)h0[j], w0, a0[j]);
    }
    if (half == 0 && p < end) {
        unsigned m0 = meta[p];
        h16x4 h0 = *(const h16x4*)(x16 + (size_t)(m0 >> 15) * 128 + cb);
        float w0 = meta_w(m0);
#pragma unroll
        for (int j = 0; j < 4; ++j) a1[j] = fmaf((float)h0[j], w0, a1[j]);
    }
#pragma unroll
    for (int j = 0; j < 4; ++j) a0[j] += a1[j];
#pragma unroll
    for (int j = 0; j < 4; ++j) a0[j] += __shfl(a0[j], lane + 32);
    if (half == 0) {
        float s = dinv[node]; s = s * s;
        h16x4 sv = *(const h16x4*)(x16 + (size_t)node * 128 + cb);
        h16x4 o;
#pragma unroll
        for (int j = 0; j < 4; ++j) o[j] = (h16)fmaf((float)sv[j], s, a0[j]);
        __builtin_nontemporal_store(o, (h16x4*)(Xa + (size_t)node * 128 + cb));
    }
}

// ---------------- gather Y = agg(P1relu) 256ch: half-wave pairing, 8ch/lane ----------------
__global__ __launch_bounds__(256) void k_gather_y(h16* __restrict__ Y,
                                                  const h16* __restrict__ P1,
                                                  const float* __restrict__ dinv,
                                                  const int* __restrict__ rowptr,
                                                  const unsigned* __restrict__ meta, int n) {
    int node = (blockIdx.x << 2) + (threadIdx.x >> 6);
    if (node >= n) return;
    const int lane = threadIdx.x & 63;
    const int half = lane >> 5;
    const int cb = (lane & 31) << 3;
    float a0[8] = {}, a1[8] = {};
    int p = rowptr[node];
    const int end = rowptr[node + 1];
    for (; p + 3 < end; p += 4) {
        unsigned m0 = meta[p + half], m1 = meta[p + half + 2];
        h16x8 h0 = *(const h16x8*)(P1 + (size_t)(m0 >> 15) * 256 + cb);
        h16x8 h1 = *(const h16x8*)(P1 + (size_t)(m1 >> 15) * 256 + cb);
        float w0 = meta_w(m0), w1 = meta_w(m1);
#pragma unroll
        for (int j = 0; j < 8; ++j) {
            a0[j] = fmaf((float)h0[j], w0, a0[j]);
            a1[j] = fmaf((float)h1[j], w1, a1[j]);
        }
    }
    for (; p + 1 < end; p += 2) {
        unsigned m0 = meta[p + half];
        h16x8 h0 = *(const h16x8*)(P1 + (size_t)(m0 >> 15) * 256 + cb);
        float w0 = meta_w(m0);
#pragma unroll
        for (int j = 0; j < 8; ++j) a0[j] = fmaf((float)h0[j], w0, a0[j]);
    }
    if (half == 0 && p < end) {
        unsigned m0 = meta[p];
        h16x8 h0 = *(const h16x8*)(P1 + (size_t)(m0 >> 15) * 256 + cb);
        float w0 = meta_w(m0);
#pragma unroll
        for (int j = 0; j < 8; ++j) a1[j] = fmaf((float)h0[j], w0, a1[j]);
    }
#pragma unroll
    for (int j = 0; j < 8; ++j) a0[j] += a1[j];
#pragma unroll
    for (int j = 0; j < 8; ++j) a0[j] += __shfl(a0[j], lane + 32);
    if (half == 0) {
        float s = dinv[node]; s = s * s;
        h16x8 sv = *(const h16x8*)(P1 + (size_t)node * 256 + cb);
        h16x8 o;
#pragma unroll
        for (int j = 0; j < 8; ++j) o[j] = (h16)fmaf((float)sv[j], s, a0[j]);
        __builtin_nontemporal_store(o, (h16x8*)(Y + (size_t)node * 256 + cb));
    }
}

// ---------------- fp16 2-product MFMA GEMM: Out = relu(A @ (Wh+Wl)^T/64 + b), fp16 ----------------
template<bool NT>
__global__ __launch_bounds__(256) void k_gemm(const h16* __restrict__ Ag,
                                              const h16* __restrict__ Bhg,
                                              const h16* __restrict__ Blg,
                                              h16* __restrict__ Out,
                                              const float* __restrict__ bias,
                                              int M, int K) {
    __shared__ __attribute__((aligned(16))) char ldsA[8192];
    __shared__ __attribute__((aligned(16))) char ldsBh[8192];
    __shared__ __attribute__((aligned(16))) char ldsBl[8192];
    const int tid = threadIdx.x;
    const int lane = tid & 63, wid = tid >> 6;
    const int quad = lane >> 4, l16 = lane & 15;
    const int rowBase = blockIdx.x * 128;
    const int colBase = blockIdx.y * 128;
    const int wm = (wid & 1) * 64, wn = (wid >> 1) * 64;

    floatx4 acc[4][4] = {};

    const int c0 = wid * 64 + lane;
    const int c1 = c0 + 256;
    const int r0 = ((c0 >> 6) << 4) + (c0 & 15), q0 = (c0 >> 4) & 3;
    const int r1 = ((c1 >> 6) << 4) + (c1 & 15), q1 = (c1 >> 4) & 3;
    const size_t aoff0 = (size_t)(rowBase + r0) * K + q0 * 8;
    const size_t aoff1 = (size_t)(rowBase + r1) * K + q1 * 8;
    const size_t boff0 = (size_t)(colBase + r0) * K + q0 * 8;
    const size_t boff1 = (size_t)(colBase + r1) * K + q1 * 8;
    const int lo0 = (wid * 64) * 16;
    const int lo1 = (256 + wid * 64) * 16;

    for (int k0 = 0; k0 < K; k0 += 32) {
        load_lds16(ldsA + lo0, Ag + aoff0 + k0);
        load_lds16(ldsA + lo1, Ag + aoff1 + k0);
        load_lds16(ldsBh + lo0, Bhg + boff0 + k0);
        load_lds16(ldsBh + lo1, Bhg + boff1 + k0);
        load_lds16(ldsBl + lo0, Blg + boff0 + k0);
        load_lds16(ldsBl + lo1, Blg + boff1 + k0);
        __syncthreads();

        const half8* vA  = (const half8*)ldsA;
        const half8* vBh = (const half8*)ldsBh;
        const half8* vBl = (const half8*)ldsBl;
        half8 af[4], bfh[4], bfl[4];
#pragma unroll
        for (int mi = 0; mi < 4; ++mi)
            af[mi] = vA[((wm >> 4) + mi) * 64 + quad * 16 + l16];
#pragma unroll
        for (int ni = 0; ni < 4; ++ni) {
            int idx = ((wn >> 4) + ni) * 64 + quad * 16 + l16;
            bfh[ni] = vBh[idx];
            bfl[ni] = vBl[idx];
        }
#pragma unroll
        for (int mi = 0; mi < 4; ++mi)
#pragma unroll
            for (int ni = 0; ni < 4; ++ni) {
                acc[mi][ni] = __builtin_amdgcn_mfma_f32_16x16x32_f16(af[mi], bfh[ni], acc[mi][ni], 0, 0, 0);
                acc[mi][ni] = __builtin_amdgcn_mfma_f32_16x16x32_f16(af[mi], bfl[ni], acc[mi][ni], 0, 0, 0);
            }
        __syncthreads();
    }

#pragma unroll
    for (int mi = 0; mi < 4; ++mi) {
#pragma unroll
        for (int r = 0; r < 4; ++r) {
            int grow = rowBase + wm + mi * 16 + quad * 4 + r;
            if (grow < M) {
#pragma unroll
                for (int ni = 0; ni < 4; ++ni) {
                    int gcol = colBase + wn + ni * 16 + l16;
                    float v = fmaxf(acc[mi][ni][r] * WINV + bias[gcol], 0.f);
                    if (NT) __builtin_nontemporal_store((h16)v, Out + (size_t)grow * 256 + gcol);
                    else Out[(size_t)grow * 256 + gcol] = (h16)v;
                }
            }
        }
    }
}

// ---------------- MFMA FC: out[M,40] = X[M,256]fp16 @ fcW[256,40] + fcb ----------------
// N padded 40->48 (3 n-tiles); fcW staged to LDS fp16 chunk layout once; 128-row blocks.
__global__ __launch_bounds__(256) void k_fc(float* __restrict__ out, const h16* __restrict__ X,
                                            const float* __restrict__ W, const float* __restrict__ bias,
                                            int M) {
    __shared__ __attribute__((aligned(16))) char ldsB[24576];  // 3 ntile x 8 kstep x 64 chunks x 16B
    __shared__ __attribute__((aligned(16))) char ldsA[8192];   // 128 rows x 32 k fp16 (chunked)
    const int tid = threadIdx.x;
    const int lane = tid & 63, wid = tid >> 6;
    const int quad = lane >> 4, l16 = lane & 15;
    const int rowBase = blockIdx.x * 128;

    // stage fcW^T (fp16, pad cols 40->48) in MFMA chunk layout
    for (int c = tid; c < 1536; c += 256) {
        int idx = c & 63, s = (c >> 6) & 7, t = c >> 9;
        int q = idx >> 4, nn = t * 16 + (idx & 15);
        int kb = s * 32 + q * 8;
        h16x8 v = {};
        if (nn < 40) {
#pragma unroll
            for (int j = 0; j < 8; ++j) v[j] = (h16)W[(kb + j) * 40 + nn];
        }
        *reinterpret_cast<h16x8*>(ldsB + c * 16) = v;
    }

    floatx4 acc[2][3] = {};
    const int c0 = wid * 64 + lane;
    const int c1 = c0 + 256;
    const int r0 = ((c0 >> 6) << 4) + (c0 & 15), q0 = (c0 >> 4) & 3;
    const int r1 = ((c1 >> 6) << 4) + (c1 & 15), q1 = (c1 >> 4) & 3;

    for (int s = 0; s < 8; ++s) {
        int k0 = s * 32;
        load_lds16(ldsA + c0 * 16, X + (size_t)(rowBase + r0) * 256 + k0 + q0 * 8);
        load_lds16(ldsA + c1 * 16, X + (size_t)(rowBase + r1) * 256 + k0 + q1 * 8);
        __syncthreads();   // drains LDS-writes (incl. ldsB fill on s=0) + global_load_lds
        const half8* vA = (const half8*)ldsA;
        const half8* vB = (const half8*)ldsB;
        half8 af[2];
#pragma unroll
        for (int mi = 0; mi < 2; ++mi)
            af[mi] = vA[(wid * 2 + mi) * 64 + quad * 16 + l16];
#pragma unroll
        for (int t = 0; t < 3; ++t) {
            half8 bf = vB[(t * 8 + s) * 64 + quad * 16 + l16];
#pragma unroll
            for (int mi = 0; mi < 2; ++mi)
                acc[mi][t] = __builtin_amdgcn_mfma_f32_16x16x32_f16(af[mi], bf, acc[mi][t], 0, 0, 0);
        }
        __syncthreads();
    }

#pragma unroll
    for (int mi = 0; mi < 2; ++mi)
#pragma unroll
        for (int r = 0; r < 4; ++r) {
            int grow = rowBase + wid * 32 + mi * 16 + quad * 4 + r;
            if (grow < M) {
#pragma unroll
                for (int t = 0; t < 3; ++t) {
                    int gcol = t * 16 + l16;
                    if (gcol < 40)
                        out[(size_t)grow * 40 + gcol] = acc[mi][t][r] + bias[gcol];
                }
            }
        }
}

extern "C" void kernel_launch(void* const* d_in, const int* in_sizes, int n_in,
                              void* d_out, int out_size, void* d_ws, size_t ws_size,
                              hipStream_t stream) {
    const float* x   = (const float*)d_in[0];
    const int*   ei  = (const int*)d_in[1];
    const float* ea  = (const float*)d_in[2];
    const float* W1  = (const float*)d_in[3];
    const float* b1  = (const float*)d_in[4];
    const float* W2  = (const float*)d_in[5];
    const float* b2  = (const float*)d_in[6];
    const float* fcW = (const float*)d_in[7];
    const float* fcb = (const float*)d_in[8];
    float* out = (float*)d_out;

    const int n = NODES, e = EDGES;
    const int* row = ei;
    const int* col = ei + e;

    char* ws = (char*)d_ws;
    char*  Areg   = ws;                                        // 102,400,000 B
    char*  Breg   = ws + 102400000u;                           // 102,400,000 B
    float* dinv   = (float*)(ws + 204800000u);                 // 400,000 B
    unsigned long long* packed = (unsigned long long*)(ws + 205200000u); // 800,000 B
    int*   rowptr = (int*)  (ws + 206000000u);                 // 400,016 B
    unsigned* meta = (unsigned*)(ws + 206400016u);             // 6,400,000 B -> 212,800,016
    h16*   W1h    = (h16*)  (ws + 212800016u);                 // 65,536 B
    h16*   W1l    = (h16*)  (ws + 212865552u);                 // 65,536 B
    h16*   W2h    = (h16*)  (ws + 212931088u);                 // 131,072 B
    h16*   W2l    = (h16*)  (ws + 213062160u);                 // 131,072 B -> 213,193,232

    // overlays (time-shared):
    int* partials = (int*)Areg;                                // scan temp (dies after scan3)
    h16* Xa16 = (h16*)Areg;                                    // 25.6 MB agg(x) [after scan3]
    h16* x16  = (h16*)(Areg + 25600000u);                      // 25.6 MB fp16 x
    h16* Yh   = (h16*)Areg;                                    // 51.2 MB Y = agg(P1relu) [after gemm1]
    unsigned short* rank = (unsigned short*)Breg;              // 3.2 MB (dies after build)
    h16* P1   = (h16*)Breg;                                    // 51.2 MB relu(P1) fp16 [after build]
    h16* P2h  = (h16*)(Breg + 51200000u);                      // 51.2 MB relu(P2) fp16 [gemm2 out]

    const int nb = (n + 255) / 256;   // 391
    const int eb = e / 256;           // 6250

    // ---- CSR build + fused conversions ----
    k_init<<<nb, 256, 0, stream>>>(packed, n);
    k_hist<<<19134, 256, 0, stream>>>(packed, rank, col, ea, e,
                                      W1, W1h, W1l, W2, W2h, W2l, x, x16, n);
    k_scan1<<<nb, 256, 0, stream>>>(packed, rowptr, partials, dinv, n);
    k_scan3<<<nb, 256, 0, stream>>>(rowptr, partials, n);
    k_build<<<eb, 256, 0, stream>>>(rowptr, rank, meta, row, col, ea, dinv, e);

    dim3 gg((n + 127) / 128, 2);

    // layer 1 (agg-first): Xa = agg(x16) ; P1 = relu(Xa@W1 + b1) fp16
    k_gather_x<<<(n + 3) / 4, 256, 0, stream>>>(Xa16, x16, dinv, rowptr, meta, n);
    k_gemm<false><<<gg, 256, 0, stream>>>(Xa16, W1h, W1l, P1, b1, n, 128);

    // layer 2 (agg-first): Y = agg(P1) ; P2 = relu(Y@W2 + b2) fp16 (NT store, read once)
    k_gather_y<<<(n + 3) / 4, 256, 0, stream>>>(Yh, P1, dinv, rowptr, meta, n);
    k_gemm<true><<<gg, 256, 0, stream>>>(Yh, W2h, W2l, P2h, b2, n, 256);

    // classifier (MFMA)
    k_fc<<<(n + 127) / 128, 256, 0, stream>>>(out, P2h, fcW, fcb, n);
}

// Round 13
// 538.858 us; speedup vs baseline: 1.2331x; 1.0318x over previous
//
#include <hip/hip_runtime.h>

#define NODES 100000
#define EDGES 1600000

typedef __attribute__((ext_vector_type(4))) float floatx4;
typedef _Float16 h16;
typedef __attribute__((ext_vector_type(4))) _Float16 h16x4;
typedef __attribute__((ext_vector_type(8))) _Float16 h16x8;
typedef __attribute__((ext_vector_type(8))) _Float16 half8;

#define WSCALE 64.0f
#define WINV   (1.0f / 64.0f)

__device__ inline void load_lds16(void* lds, const void* g) {
    __builtin_amdgcn_global_load_lds((const __attribute__((address_space(1))) void*)g,
                                     (__attribute__((address_space(3))) void*)lds, 16, 0, 0);
}

__device__ inline float meta_w(unsigned m) {
    return (float)__builtin_bit_cast(h16, (unsigned short)(m & 0x7FFFu));
}

// ---------------- fused: histogram+rank (32b packed) | W1 split | W2 split | x->fp16 ----------------
__device__ inline void w_split(const float* W, h16* Wh, h16* Wl, int idx, int K) {
    int k = idx >> 8, nn = idx & 255;
    float v = W[idx] * WSCALE;
    h16 h = (h16)v;
    h16 l = (h16)(v - (float)h);
    Wh[nn * K + k] = h;
    Wl[nn * K + k] = l;
}

__global__ __launch_bounds__(256) void k_hist(unsigned* __restrict__ packed,
                                              unsigned short* __restrict__ rank,
                                              const int* __restrict__ col,
                                              const float* __restrict__ ew, int e,
                                              const float* __restrict__ W1, h16* __restrict__ W1h, h16* __restrict__ W1l,
                                              const float* __restrict__ W2, h16* __restrict__ W2h, h16* __restrict__ W2l,
                                              const float* __restrict__ x, h16* __restrict__ x16, int n) {
    int b = blockIdx.x;
    if (b < 6250) {
        int i = b * 256 + threadIdx.x;
        if (i < e) {
            int c = __builtin_nontemporal_load(col + i);
            float w = __builtin_nontemporal_load(ew + i);
            // pack: cnt in bits[25:31] (max deg << 127), fix18 weight-sum in [0:25)
            unsigned v = (1u << 25) | __float2uint_rn(w * 262144.0f);
            unsigned old = atomicAdd(&packed[c], v);
            rank[i] = (unsigned short)(old >> 25);
        }
    } else if (b < 6378) {
        w_split(W1, W1h, W1l, (b - 6250) * 256 + threadIdx.x, 128);
    } else if (b < 6634) {
        w_split(W2, W2h, W2l, (b - 6378) * 256 + threadIdx.x, 256);
    } else {
        int i = (b - 6634) * 256 + threadIdx.x;
        if (i < n * 32) {
            float4 v = reinterpret_cast<const float4*>(x)[i];
            h16x4 h;
            h.x = (h16)v.x; h.y = (h16)v.y; h.z = (h16)v.z; h.w = (h16)v.w;
            reinterpret_cast<h16x4*>(x16)[i] = h;
        }
    }
}

// ---------------- scan phase 1: unpack cnt, dinv, per-block exclusive scan ----------------
__global__ __launch_bounds__(256) void k_scan1(const unsigned* __restrict__ packed,
                                               int* __restrict__ rowptr,
                                               int* __restrict__ partials,
                                               float* __restrict__ dinv, int n) {
    __shared__ int wtot[4];
    const int tid = threadIdx.x, lane = tid & 63, wid = tid >> 6;
    int i = blockIdx.x * 256 + tid;
    int v = 0;
    if (i < n) {
        unsigned p = packed[i];
        v = (int)(p >> 25);
        float deg = 1.0f + (float)(p & 0x1FFFFFFu) * (1.0f / 262144.0f);
        dinv[i] = rsqrtf(deg);
    }
    int incl = v;
#pragma unroll
    for (int off = 1; off < 64; off <<= 1) {
        int t = __shfl_up(incl, off, 64);
        if (lane >= off) incl += t;
    }
    if (lane == 63) wtot[wid] = incl;
    __syncthreads();
    int woff = 0;
    for (int k = 0; k < wid; ++k) woff += wtot[k];
    if (i < n) rowptr[i] = woff + incl - v;
    if (tid == 255) partials[blockIdx.x] = woff + incl;
}

// ---------------- scan phase 2+3 fused ----------------
__global__ __launch_bounds__(256) void k_scan3(int* __restrict__ rowptr,
                                               const int* __restrict__ partials, int n) {
    __shared__ int wsum[4];
    const int tid = threadIdx.x, lane = tid & 63, wid = tid >> 6;
    const int b = blockIdx.x;
    int v = 0;
    for (int t = tid; t < b; t += 256) v += partials[t];
#pragma unroll
    for (int off = 32; off > 0; off >>= 1) v += __shfl_down(v, off, 64);
    if (lane == 0) wsum[wid] = v;
    __syncthreads();
    int base = wsum[0] + wsum[1] + wsum[2] + wsum[3];
    int i = b * 256 + tid;
    if (i < n) rowptr[i] += base;
    if (b == 0 && tid == 0) rowptr[n] = EDGES;
}

// ---------------- CSR build: atomic-free, packed 4B meta = (row<<15)|fp16(w) ----------------
__global__ __launch_bounds__(256) void k_build(const int* __restrict__ rowptr,
                                               const unsigned short* __restrict__ rank,
                                               unsigned* __restrict__ meta,
                                               const int* __restrict__ row, const int* __restrict__ col,
                                               const float* __restrict__ ew,
                                               const float* __restrict__ dinv, int e) {
    int i = blockIdx.x * 256 + threadIdx.x;
    if (i >= e) return;
    int r = __builtin_nontemporal_load(row + i);
    int c = __builtin_nontemporal_load(col + i);
    float w0 = __builtin_nontemporal_load(ew + i);
    float w = dinv[r] * w0 * dinv[c];     // w >= 0 always
    unsigned short wb = __builtin_bit_cast(unsigned short, (h16)w);
    meta[rowptr[c] + rank[i]] = ((unsigned)r << 15) | wb;
}

// ---------------- gather agg(x16) 128ch: half-wave pairing, 4ch/lane ----------------
__global__ __launch_bounds__(256) void k_gather_x(h16* __restrict__ Xa,
                                                  const h16* __restrict__ x16,
                                                  const float* __restrict__ dinv,
                                                  const int* __restrict__ rowptr,
                                                  const unsigned* __restrict__ meta, int n) {
    int node = (blockIdx.x << 2) + (threadIdx.x >> 6);
    if (node >= n) return;
    const int lane = threadIdx.x & 63;
    const int half = lane >> 5;
    const int cb = (lane & 31) << 2;
    float a0[4] = {}, a1[4] = {};
    int p = rowptr[node];
    const int end = rowptr[node + 1];
    for (; p + 3 < end; p += 4) {
        unsigned m0 = meta[p + half], m1 = meta[p + half + 2];
        h16x4 h0 = *(const h16x4*)(x16 + (size_t)(m0 >> 15) * 128 + cb);
        h16x4 h1 = *(const h16x4*)(x16 + (size_t)(m1 >> 15) * 128 + cb);
        float w0 = meta_w(m0), w1 = meta_w(m1);
#pragma unroll
        for (int j = 0; j < 4; ++j) {
            a0[j] = fmaf((float)h0[j], w0, a0[j]);
            a1[j] = fmaf((float)h1[j], w1, a1[j]);
        }
    }
    for (; p + 1 < end; p += 2) {
        unsigned m0 = meta[p + half];
        h16x4 h0 = *(const h16x4*)(x16 + (size_t)(m0 >> 15) * 128 + cb);
        float w0 = meta_w(m0);
#pragma unroll
        for (int j = 0; j < 4; ++j) a0[j] = fmaf((float)h0[j], w0, a0[j]);
    }
    if (half == 0 && p < end) {
        unsigned m0 = meta[p];
        h16x4 h0 = *(const h16x4*)(x16 + (size_t)(m0 >> 15) * 128 + cb);
        float w0 = meta_w(m0);
#pragma unroll
        for (int j = 0; j < 4; ++j) a1[j] = fmaf((float)h0[j], w0, a1[j]);
    }
#pragma unroll
    for (int j = 0; j < 4; ++j) a0[j] += a1[j];
#pragma unroll
    for (int j = 0; j < 4; ++j) a0[j] += __shfl(a0[j], lane + 32);
    if (half == 0) {
        float s = dinv[node]; s = s * s;
        h16x4 sv = *(const h16x4*)(x16 + (size_t)node * 128 + cb);
        h16x4 o;
#pragma unroll
        for (int j = 0; j < 4; ++j) o[j] = (h16)fmaf((float)sv[j], s, a0[j]);
        __builtin_nontemporal_store(o, (h16x4*)(Xa + (size_t)node * 128 + cb));
    }
}

// ---------------- gather Y = agg(P1relu) 256ch: half-wave pairing, 8ch/lane ----------------
__global__ __launch_bounds__(256) void k_gather_y(h16* __restrict__ Y,
                                                  const h16* __restrict__ P1,
                                                  const float* __restrict__ dinv,
                                                  const int* __restrict__ rowptr,
                                                  const unsigned* __restrict__ meta, int n) {
    int node = (blockIdx.x << 2) + (threadIdx.x >> 6);
    if (node >= n) return;
    const int lane = threadIdx.x & 63;
    const int half = lane >> 5;
    const int cb = (lane & 31) << 3;
    float a0[8] = {}, a1[8] = {};
    int p = rowptr[node];
    const int end = rowptr[node + 1];
    for (; p + 3 < end; p += 4) {
        unsigned m0 = meta[p + half], m1 = meta[p + half + 2];
        h16x8 h0 = *(const h16x8*)(P1 + (size_t)(m0 >> 15) * 256 + cb);
        h16x8 h1 = *(const h16x8*)(P1 + (size_t)(m1 >> 15) * 256 + cb);
        float w0 = meta_w(m0), w1 = meta_w(m1);
#pragma unroll
        for (int j = 0; j < 8; ++j) {
            a0[j] = fmaf((float)h0[j], w0, a0[j]);
            a1[j] = fmaf((float)h1[j], w1, a1[j]);
        }
    }
    for (; p + 1 < end; p += 2) {
        unsigned m0 = meta[p + half];
        h16x8 h0 = *(const h16x8*)(P1 + (size_t)(m0 >> 15) * 256 + cb);
        float w0 = meta_w(m0);
#pragma unroll
        for (int j = 0; j < 8; ++j) a0[j] = fmaf((float)h0[j], w0, a0[j]);
    }
    if (half == 0 && p < end) {
        unsigned m0 = meta[p];
        h16x8 h0 = *(const h16x8*)(P1 + (size_t)(m0 >> 15) * 256 + cb);
        float w0 = meta_w(m0);
#pragma unroll
        for (int j = 0; j < 8; ++j) a1[j] = fmaf((float)h0[j], w0, a1[j]);
    }
#pragma unroll
    for (int j = 0; j < 8; ++j) a0[j] += a1[j];
#pragma unroll
    for (int j = 0; j < 8; ++j) a0[j] += __shfl(a0[j], lane + 32);
    if (half == 0) {
        float s = dinv[node]; s = s * s;
        h16x8 sv = *(const h16x8*)(P1 + (size_t)node * 256 + cb);
        h16x8 o;
#pragma unroll
        for (int j = 0; j < 8; ++j) o[j] = (h16)fmaf((float)sv[j], s, a0[j]);
        __builtin_nontemporal_store(o, (h16x8*)(Y + (size_t)node * 256 + cb));
    }
}

// ---------------- fp16 2-product MFMA GEMM, full-N 128x256 tile ----------------
// Out = relu(A @ (Wh+Wl)^T/64 + b) fp16. A [M,K], Wh/Wl [256,K] (x64 scaled).
// 40KB LDS, acc[4][8], A read ONCE per pass.
template<bool NT>
__global__ __launch_bounds__(256, 2) void k_gemm(const h16* __restrict__ Ag,
                                                 const h16* __restrict__ Bhg,
                                                 const h16* __restrict__ Blg,
                                                 h16* __restrict__ Out,
                                                 const float* __restrict__ bias,
                                                 int M, int K) {
    __shared__ __attribute__((aligned(16))) char ldsA[8192];    // 128 rows x 32k
    __shared__ __attribute__((aligned(16))) char ldsBh[16384];  // 256 n x 32k
    __shared__ __attribute__((aligned(16))) char ldsBl[16384];
    const int tid = threadIdx.x;
    const int lane = tid & 63, wid = tid >> 6;
    const int quad = lane >> 4, l16 = lane & 15;
    const int rowBase = blockIdx.x * 128;
    const int wm = (wid & 1) * 64, wn = (wid >> 1) * 128;

    floatx4 acc[4][8] = {};

    const int cA0 = wid * 64 + lane;
    const int cA1 = cA0 + 256;
    const int rA0 = ((cA0 >> 6) << 4) + (cA0 & 15), qA0 = (cA0 >> 4) & 3;
    const int rA1 = ((cA1 >> 6) << 4) + (cA1 & 15), qA1 = (cA1 >> 4) & 3;
    const size_t aoff0 = (size_t)(rowBase + rA0) * K + qA0 * 8;
    const size_t aoff1 = (size_t)(rowBase + rA1) * K + qA1 * 8;

    for (int k0 = 0; k0 < K; k0 += 32) {
        load_lds16(ldsA + cA0 * 16, Ag + aoff0 + k0);
        load_lds16(ldsA + cA1 * 16, Ag + aoff1 + k0);
#pragma unroll
        for (int i = 0; i < 4; ++i) {
            int c = tid + i * 256;                       // 0..1023
            int r = ((c >> 6) << 4) + (c & 15);          // 0..255
            int q = (c >> 4) & 3;
            size_t go = (size_t)r * K + k0 + q * 8;
            load_lds16(ldsBh + c * 16, Bhg + go);
            load_lds16(ldsBl + c * 16, Blg + go);
        }
        __syncthreads();

        const half8* vA  = (const half8*)ldsA;
        const half8* vBh = (const half8*)ldsBh;
        const half8* vBl = (const half8*)ldsBl;
        half8 af[4];
#pragma unroll
        for (int mi = 0; mi < 4; ++mi)
            af[mi] = vA[((wm >> 4) + mi) * 64 + quad * 16 + l16];
#pragma unroll
        for (int ni = 0; ni < 8; ++ni) {
            int idx = ((wn >> 4) + ni) * 64 + quad * 16 + l16;
            half8 bh = vBh[idx];
            half8 bl = vBl[idx];
#pragma unroll
            for (int mi = 0; mi < 4; ++mi) {
                acc[mi][ni] = __builtin_amdgcn_mfma_f32_16x16x32_f16(af[mi], bh, acc[mi][ni], 0, 0, 0);
                acc[mi][ni] = __builtin_amdgcn_mfma_f32_16x16x32_f16(af[mi], bl, acc[mi][ni], 0, 0, 0);
            }
        }
        __syncthreads();
    }

#pragma unroll
    for (int mi = 0; mi < 4; ++mi) {
#pragma unroll
        for (int r = 0; r < 4; ++r) {
            int grow = rowBase + wm + mi * 16 + quad * 4 + r;
            if (grow < M) {
#pragma unroll
                for (int ni = 0; ni < 8; ++ni) {
                    int gcol = wn + ni * 16 + l16;
                    float v = fmaxf(acc[mi][ni][r] * WINV + bias[gcol], 0.f);
                    if (NT) __builtin_nontemporal_store((h16)v, Out + (size_t)grow * 256 + gcol);
                    else Out[(size_t)grow * 256 + gcol] = (h16)v;
                }
            }
        }
    }
}

// ---------------- MFMA FC: out[M,40] = X[M,256]fp16 @ fcW[256,40] + fcb ----------------
__global__ __launch_bounds__(256) void k_fc(float* __restrict__ out, const h16* __restrict__ X,
                                            const float* __restrict__ W, const float* __restrict__ bias,
                                            int M) {
    __shared__ __attribute__((aligned(16))) char ldsB[24576];  // 3 ntile x 8 kstep x 64 chunks x 16B
    __shared__ __attribute__((aligned(16))) char ldsA[8192];   // 128 rows x 32 k fp16 (chunked)
    const int tid = threadIdx.x;
    const int lane = tid & 63, wid = tid >> 6;
    const int quad = lane >> 4, l16 = lane & 15;
    const int rowBase = blockIdx.x * 128;

    for (int c = tid; c < 1536; c += 256) {
        int idx = c & 63, s = (c >> 6) & 7, t = c >> 9;
        int q = idx >> 4, nn = t * 16 + (idx & 15);
        int kb = s * 32 + q * 8;
        h16x8 v = {};
        if (nn < 40) {
#pragma unroll
            for (int j = 0; j < 8; ++j) v[j] = (h16)W[(kb + j) * 40 + nn];
        }
        *reinterpret_cast<h16x8*>(ldsB + c * 16) = v;
    }

    floatx4 acc[2][3] = {};
    const int c0 = wid * 64 + lane;
    const int c1 = c0 + 256;
    const int r0 = ((c0 >> 6) << 4) + (c0 & 15), q0 = (c0 >> 4) & 3;
    const int r1 = ((c1 >> 6) << 4) + (c1 & 15), q1 = (c1 >> 4) & 3;

    for (int s = 0; s < 8; ++s) {
        int k0 = s * 32;
        load_lds16(ldsA + c0 * 16, X + (size_t)(rowBase + r0) * 256 + k0 + q0 * 8);
        load_lds16(ldsA + c1 * 16, X + (size_t)(rowBase + r1) * 256 + k0 + q1 * 8);
        __syncthreads();
        const half8* vA = (const half8*)ldsA;
        const half8* vB = (const half8*)ldsB;
        half8 af[2];
#pragma unroll
        for (int mi = 0; mi < 2; ++mi)
            af[mi] = vA[(wid * 2 + mi) * 64 + quad * 16 + l16];
#pragma unroll
        for (int t = 0; t < 3; ++t) {
            half8 bf = vB[(t * 8 + s) * 64 + quad * 16 + l16];
#pragma unroll
            for (int mi = 0; mi < 2; ++mi)
                acc[mi][t] = __builtin_amdgcn_mfma_f32_16x16x32_f16(af[mi], bf, acc[mi][t], 0, 0, 0);
        }
        __syncthreads();
    }

#pragma unroll
    for (int mi = 0; mi < 2; ++mi)
#pragma unroll
        for (int r = 0; r < 4; ++r) {
            int grow = rowBase + wid * 32 + mi * 16 + quad * 4 + r;
            if (grow < M) {
#pragma unroll
                for (int t = 0; t < 3; ++t) {
                    int gcol = t * 16 + l16;
                    if (gcol < 40)
                        out[(size_t)grow * 40 + gcol] = acc[mi][t][r] + bias[gcol];
                }
            }
        }
}

extern "C" void kernel_launch(void* const* d_in, const int* in_sizes, int n_in,
                              void* d_out, int out_size, void* d_ws, size_t ws_size,
                              hipStream_t stream) {
    const float* x   = (const float*)d_in[0];
    const int*   ei  = (const int*)d_in[1];
    const float* ea  = (const float*)d_in[2];
    const float* W1  = (const float*)d_in[3];
    const float* b1  = (const float*)d_in[4];
    const float* W2  = (const float*)d_in[5];
    const float* b2  = (const float*)d_in[6];
    const float* fcW = (const float*)d_in[7];
    const float* fcb = (const float*)d_in[8];
    float* out = (float*)d_out;

    const int n = NODES, e = EDGES;
    const int* row = ei;
    const int* col = ei + e;

    char* ws = (char*)d_ws;
    char*  Areg   = ws;                                        // 102,400,000 B
    char*  Breg   = ws + 102400000u;                           // 102,400,000 B
    float* dinv   = (float*)(ws + 204800000u);                 // 400,000 B
    unsigned* packed = (unsigned*)(ws + 205200000u);           // 400,000 B
    int*   rowptr = (int*)  (ws + 205600000u);                 // 400,016 B
    unsigned* meta = (unsigned*)(ws + 206000016u);             // 6,400,000 B -> 212,400,016
    h16*   W1h    = (h16*)  (ws + 212400016u);                 // 65,536 B
    h16*   W1l    = (h16*)  (ws + 212465552u);                 // 65,536 B
    h16*   W2h    = (h16*)  (ws + 212531088u);                 // 131,072 B
    h16*   W2l    = (h16*)  (ws + 212662160u);                 // 131,072 B -> 212,793,232

    // overlays (time-shared):
    int* partials = (int*)Areg;                                // scan temp (dies after scan3)
    h16* Xa16 = (h16*)Areg;                                    // 25.6 MB agg(x) [after scan3]
    h16* x16  = (h16*)(Areg + 25600000u);                      // 25.6 MB fp16 x
    h16* Yh   = (h16*)Areg;                                    // 51.2 MB Y = agg(P1relu) [after gemm1]
    unsigned short* rank = (unsigned short*)Breg;              // 3.2 MB (dies after build)
    h16* P1   = (h16*)Breg;                                    // 51.2 MB relu(P1) fp16 [after build]
    h16* P2h  = (h16*)(Breg + 51200000u);                      // 51.2 MB relu(P2) fp16 [gemm2 out]

    const int nb = (n + 255) / 256;   // 391
    const int eb = e / 256;           // 6250

    // ---- CSR build + fused conversions ----
    hipMemsetAsync(packed, 0, 400000u, stream);
    k_hist<<<19134, 256, 0, stream>>>(packed, rank, col, ea, e,
                                      W1, W1h, W1l, W2, W2h, W2l, x, x16, n);
    k_scan1<<<nb, 256, 0, stream>>>(packed, rowptr, partials, dinv, n);
    k_scan3<<<nb, 256, 0, stream>>>(rowptr, partials, n);
    k_build<<<eb, 256, 0, stream>>>(rowptr, rank, meta, row, col, ea, dinv, e);

    const int gb = (n + 127) / 128;   // 782

    // layer 1 (agg-first): Xa = agg(x16) ; P1 = relu(Xa@W1 + b1) fp16
    k_gather_x<<<(n + 3) / 4, 256, 0, stream>>>(Xa16, x16, dinv, rowptr, meta, n);
    k_gemm<false><<<gb, 256, 0, stream>>>(Xa16, W1h, W1l, P1, b1, n, 128);

    // layer 2 (agg-first): Y = agg(P1) ; P2 = relu(Y@W2 + b2) fp16 (NT, read once)
    k_gather_y<<<(n + 3) / 4, 256, 0, stream>>>(Yh, P1, dinv, rowptr, meta, n);
    k_gemm<true><<<gb, 256, 0, stream>>>(Yh, W2h, W2l, P2h, b2, n, 256);

    // classifier (MFMA)
    k_fc<<<(n + 127) / 128, 256, 0, stream>>>(out, P2h, fcW, fcb, n);
}